// Round 11
// baseline (739.109 us; speedup 1.0000x reference)
//
#include <hip/hip_runtime.h>
#include <hip/hip_bf16.h>
#include <math.h>

#define NN 100000
#define E_RAW 1600000
#define E_TOT 1700000
#define HEADS 8
#define CH 16
#define FDIM 128
#define NCLS 40
#define SLOPE 0.2f

typedef short bf16x8 __attribute__((ext_vector_type(8)));
typedef float f32x4  __attribute__((ext_vector_type(4)));

__device__ __forceinline__ float elu1(float v) { return v > 0.f ? v : expm1f(v); }

__device__ __forceinline__ unsigned short f2bf(float f) {   // RNE bf16
    unsigned int u = __float_as_uint(f);
    u += 0x7fffu + ((u >> 16) & 1u);
    return (unsigned short)(u >> 16);
}
__device__ __forceinline__ float bf2f(unsigned short h) {
    return __uint_as_float((unsigned int)h << 16);
}

// ===== prep_w: W [k][n] fp32 -> Wt hi/lo bf16 [n][k] (split-bf16) =====
__global__ __launch_bounds__(256) void prep_w(const float* __restrict__ W1,
                                              const float* __restrict__ W2,
                                              unsigned short* __restrict__ whi1,
                                              unsigned short* __restrict__ wlo1,
                                              unsigned short* __restrict__ whi2,
                                              unsigned short* __restrict__ wlo2) {
    int t = blockIdx.x * 256 + threadIdx.x;          // 0..32767
    const float* W = (t < 16384) ? W1 : W2;
    unsigned short* hi = (t < 16384) ? whi1 : whi2;
    unsigned short* lo = (t < 16384) ? wlo1 : wlo2;
    int e = t & 16383;
    int k = e & 127, n = e >> 7;
    float v = W[k * 128 + n];
    unsigned short h = f2bf(v);
    float r = v - bf2f(h);
    hi[e] = h; lo[e] = f2bf(r);
}

// ===== MFMA GEMM [NN,128]@[128,128] -> bf16 Hb + AL/AR epilogue =====
// block: 256 thr = 4 waves; wave owns 16 rows x 128 cols; K=128 in 4 steps.
// A from global fp32 (split to hi/lo bf16 in-reg); B from pre-transposed Wt (L2-hot).
// D = A*B accuracy: ahi*bhi + alo*bhi + ahi*blo  (~fp32).
__global__ __launch_bounds__(256) void gemm_mfma(const float* __restrict__ X,
                                                 const unsigned short* __restrict__ Whi,
                                                 const unsigned short* __restrict__ Wlo,
                                                 const float* __restrict__ attl,
                                                 const float* __restrict__ attr,
                                                 unsigned short* __restrict__ Hb,
                                                 float* __restrict__ AL,
                                                 float* __restrict__ AR) {
    const int lane = threadIdx.x & 63;
    const int w    = threadIdx.x >> 6;       // wave 0..3
    const int m16  = lane & 15;              // A row / B col within frag
    const int koct = lane >> 4;              // k-octet 0..3
    const int rowA = blockIdx.x * 64 + w * 16 + m16;
    const int rowAc = rowA < NN ? rowA : NN - 1;

    f32x4 acc[8];
    #pragma unroll
    for (int c = 0; c < 8; ++c) acc[c] = (f32x4){0.f, 0.f, 0.f, 0.f};

    #pragma unroll
    for (int ks = 0; ks < 4; ++ks) {
        const int k0 = ks * 32;
        const float* xp = X + (size_t)rowAc * 128 + k0 + koct * 8;
        float xv[8];
        *(float4*)&xv[0] = *(const float4*)xp;
        *(float4*)&xv[4] = *(const float4*)(xp + 4);
        bf16x8 ahi, alo;
        #pragma unroll
        for (int j = 0; j < 8; ++j) {
            unsigned short h = f2bf(xv[j]);
            ahi[j] = (short)h;
            alo[j] = (short)f2bf(xv[j] - bf2f(h));
        }
        #pragma unroll
        for (int cf = 0; cf < 8; ++cf) {
            const size_t boff = (size_t)(cf * 16 + m16) * 128 + k0 + koct * 8;
            bf16x8 bhi = *(const bf16x8*)(Whi + boff);
            bf16x8 blo = *(const bf16x8*)(Wlo + boff);
            acc[cf] = __builtin_amdgcn_mfma_f32_16x16x32_bf16(ahi, bhi, acc[cf], 0, 0, 0);
            acc[cf] = __builtin_amdgcn_mfma_f32_16x16x32_bf16(alo, bhi, acc[cf], 0, 0, 0);
            acc[cf] = __builtin_amdgcn_mfma_f32_16x16x32_bf16(ahi, blo, acc[cf], 0, 0, 0);
        }
    }

    // epilogue: C/D layout col = lane&15, row = (lane>>4)*4 + reg  [m89]
    const int orow0 = blockIdx.x * 64 + w * 16 + koct * 4;
    #pragma unroll
    for (int cf = 0; cf < 8; ++cf) {
        const float lwv = attl[cf * 16 + m16];
        const float rwv = attr[cf * 16 + m16];
        #pragma unroll
        for (int r = 0; r < 4; ++r) {
            const int orow = orow0 + r;
            if (orow < NN)
                Hb[(size_t)orow * 128 + cf * 16 + m16] = f2bf(acc[cf][r]);
            float pl = acc[cf][r] * lwv;
            float pr = acc[cf][r] * rwv;
            #pragma unroll
            for (int off = 1; off < 16; off <<= 1) {
                pl += __shfl_xor(pl, off);
                pr += __shfl_xor(pr, off);
            }
            if (m16 == 0 && orow < NN) {
                AL[orow * 8 + cf] = pl;
                AR[orow * 8 + cf] = pr;
            }
        }
    }
}

// ================= CSR build =================
__global__ __launch_bounds__(256) void csr_init_cnt(int* __restrict__ cnt) {
    int i = blockIdx.x * 256 + threadIdx.x;
    if (i < NN) cnt[i] = 1;   // self-loop
}

__global__ __launch_bounds__(256) void csr_hist(const int* __restrict__ dst_a,
                                                int* __restrict__ cnt) {
    int e = blockIdx.x * 256 + threadIdx.x;
    if (e < E_RAW) atomicAdd(&cnt[dst_a[e]], 1);
}

__global__ __launch_bounds__(256) void scan_block(const int* __restrict__ cnt,
                                                  int* __restrict__ part,
                                                  int* __restrict__ bsum) {
    __shared__ int s[256];
    int i = blockIdx.x * 256 + threadIdx.x;
    int v = (i < NN) ? cnt[i] : 0;
    s[threadIdx.x] = v;
    __syncthreads();
    for (int off = 1; off < 256; off <<= 1) {
        int t = (threadIdx.x >= off) ? s[threadIdx.x - off] : 0;
        __syncthreads();
        s[threadIdx.x] += t;
        __syncthreads();
    }
    if (i < NN) part[i] = s[threadIdx.x] - v;
    if (threadIdx.x == 255) bsum[blockIdx.x] = s[255];
}

__global__ __launch_bounds__(512) void scan_partials(int* __restrict__ bsum, int nb) {
    __shared__ int s[512];
    int v = (threadIdx.x < nb) ? bsum[threadIdx.x] : 0;
    s[threadIdx.x] = v;
    __syncthreads();
    for (int off = 1; off < 512; off <<= 1) {
        int t = (threadIdx.x >= off) ? s[threadIdx.x - off] : 0;
        __syncthreads();
        s[threadIdx.x] += t;
        __syncthreads();
    }
    if (threadIdx.x < nb) bsum[threadIdx.x] = s[threadIdx.x] - v;
}

__global__ __launch_bounds__(256) void scan_add(const int* __restrict__ part,
                                                const int* __restrict__ bsum,
                                                int* __restrict__ roff,
                                                int* __restrict__ rpos) {
    int i = blockIdx.x * 256 + threadIdx.x;
    if (i < NN) {
        int v = part[i] + bsum[blockIdx.x];
        roff[i] = v; rpos[i] = v;
    }
    if (i == NN) roff[NN] = E_TOT;
}

__global__ __launch_bounds__(256) void csr_scatter(const int* __restrict__ src_a,
                                                   const int* __restrict__ dst_a,
                                                   int* __restrict__ rpos,
                                                   int* __restrict__ csr) {
    int e = blockIdx.x * 256 + threadIdx.x;
    if (e >= E_TOT) return;
    int s, d, flag;
    if (e < E_RAW) { s = src_a[e]; d = dst_a[e]; flag = (s == d); }
    else           { s = d = e - E_RAW; flag = 0; }
    int pos = atomicAdd(&rpos[d], 1);
    csr[pos] = s | (flag << 31);
}

// ========== fused GAT layer: online softmax + bf16 gather + bias + ELU ==========
__global__ __launch_bounds__(256) void gat_fused(const int* __restrict__ roff,
                                                 const int* __restrict__ csr,
                                                 const float* __restrict__ AL,
                                                 const float* __restrict__ AR,
                                                 const unsigned short* __restrict__ Hb,
                                                 const float* __restrict__ bias,
                                                 float* __restrict__ Out) {
    const int lane = threadIdx.x & 63;
    const int n = blockIdx.x * 4 + (threadIdx.x >> 6);
    const int r0 = roff[n], r1 = roff[n + 1];

    // ---- pass A: online segment max + denom (8 lanes per head) ----
    const int hd = lane >> 3;
    const int t  = lane & 7;
    const float ard = AR[n * 8 + hd];
    float m = -3e38f, den = 0.f;
    for (int j = r0 + t; j < r1; j += 8) {
        int sw = csr[j];
        int s = sw & 0x7fffffff;
        float ev = AL[s * 8 + hd] + ard;
        ev = fmaxf(ev, SLOPE * ev);                       // LeakyReLU
        float mn = fmaxf(m, ev);
        float add = (sw >= 0) ? __expf(ev - mn) : 0.f;    // masked dups excluded
        den = fmaf(den, __expf(m - mn), add);
        m = mn;
    }
    #pragma unroll
    for (int off = 1; off < 8; off <<= 1) {
        float m2 = __shfl_xor(m, off), d2 = __shfl_xor(den, off);
        float mn = fmaxf(m, m2);
        den = den * __expf(m - mn) + d2 * __expf(m2 - mn);
        m = mn;
    }
    const float S = m + __logf(fmaxf(den, 1e-16f));

    // ---- pass B: 8 edges/iter, 8 lanes (one head's 16 feats) per edge ----
    const int ef = lane >> 3;
    const int fl = lane & 7;
    const float S_b  = __shfl(S,   fl * 8);
    const float ar_b = __shfl(ard, fl * 8);
    float4 a0 = make_float4(0.f,0.f,0.f,0.f), a1 = a0, a2 = a0, a3 = a0;
    for (int j = r0; j < r1; j += 8) {
        int jj = j + ef;
        if (jj < r1) {
            int sw = csr[jj];
            int s = sw & 0x7fffffff;
            float ev = AL[s * 8 + fl] + ar_b;
            ev = fmaxf(ev, SLOPE * ev);
            float alpha = (sw >= 0) ? __expf(ev - S_b) : 0.f;
            const unsigned short* hp = Hb + (size_t)s * 128 + fl * 16;
            const uint4 q0 = *(const uint4*)hp;
            const uint4 q1 = *(const uint4*)(hp + 8);
            a0.x = fmaf(__uint_as_float(q0.x << 16),          alpha, a0.x);
            a0.y = fmaf(__uint_as_float(q0.x & 0xffff0000u),  alpha, a0.y);
            a0.z = fmaf(__uint_as_float(q0.y << 16),          alpha, a0.z);
            a0.w = fmaf(__uint_as_float(q0.y & 0xffff0000u),  alpha, a0.w);
            a1.x = fmaf(__uint_as_float(q0.z << 16),          alpha, a1.x);
            a1.y = fmaf(__uint_as_float(q0.z & 0xffff0000u),  alpha, a1.y);
            a1.z = fmaf(__uint_as_float(q0.w << 16),          alpha, a1.z);
            a1.w = fmaf(__uint_as_float(q0.w & 0xffff0000u),  alpha, a1.w);
            a2.x = fmaf(__uint_as_float(q1.x << 16),          alpha, a2.x);
            a2.y = fmaf(__uint_as_float(q1.x & 0xffff0000u),  alpha, a2.y);
            a2.z = fmaf(__uint_as_float(q1.y << 16),          alpha, a2.z);
            a2.w = fmaf(__uint_as_float(q1.y & 0xffff0000u),  alpha, a2.w);
            a3.x = fmaf(__uint_as_float(q1.z << 16),          alpha, a3.x);
            a3.y = fmaf(__uint_as_float(q1.z & 0xffff0000u),  alpha, a3.y);
            a3.z = fmaf(__uint_as_float(q1.w << 16),          alpha, a3.z);
            a3.w = fmaf(__uint_as_float(q1.w & 0xffff0000u),  alpha, a3.w);
        }
    }
    #pragma unroll
    for (int off = 8; off < 64; off <<= 1) {
        a0.x += __shfl_xor(a0.x, off); a0.y += __shfl_xor(a0.y, off);
        a0.z += __shfl_xor(a0.z, off); a0.w += __shfl_xor(a0.w, off);
        a1.x += __shfl_xor(a1.x, off); a1.y += __shfl_xor(a1.y, off);
        a1.z += __shfl_xor(a1.z, off); a1.w += __shfl_xor(a1.w, off);
        a2.x += __shfl_xor(a2.x, off); a2.y += __shfl_xor(a2.y, off);
        a2.z += __shfl_xor(a2.z, off); a2.w += __shfl_xor(a2.w, off);
        a3.x += __shfl_xor(a3.x, off); a3.y += __shfl_xor(a3.y, off);
        a3.z += __shfl_xor(a3.z, off); a3.w += __shfl_xor(a3.w, off);
    }
    if (lane < 8) {
        const float4* bp = (const float4*)(bias + lane * 16);
        float4 b0 = bp[0], b1 = bp[1], b2 = bp[2], b3 = bp[3];
        a0.x = elu1(a0.x + b0.x); a0.y = elu1(a0.y + b0.y);
        a0.z = elu1(a0.z + b0.z); a0.w = elu1(a0.w + b0.w);
        a1.x = elu1(a1.x + b1.x); a1.y = elu1(a1.y + b1.y);
        a1.z = elu1(a1.z + b1.z); a1.w = elu1(a1.w + b1.w);
        a2.x = elu1(a2.x + b2.x); a2.y = elu1(a2.y + b2.y);
        a2.z = elu1(a2.z + b2.z); a2.w = elu1(a2.w + b2.w);
        a3.x = elu1(a3.x + b3.x); a3.y = elu1(a3.y + b3.y);
        a3.z = elu1(a3.z + b3.z); a3.w = elu1(a3.w + b3.w);
        float4* op = (float4*)(Out + (size_t)n * 128 + lane * 16);
        op[0] = a0; op[1] = a1; op[2] = a2; op[3] = a3;
    }
}

// ================= classifier: [NN,128] @ [128,40] + bc =================
__global__ __launch_bounds__(256) void classifier(const float* __restrict__ X,
                                                  const float* __restrict__ Wc,
                                                  const float* __restrict__ bc,
                                                  float* __restrict__ Out) {
    __shared__ float ws[128 * NCLS];
    __shared__ float xs[32][132];
    for (int i = threadIdx.x; i < 128 * NCLS; i += 256) ws[i] = Wc[i];
    const int row0 = blockIdx.x << 5;
    for (int i = threadIdx.x; i < 32 * 128; i += 256) {
        int r = i >> 7, k = i & 127;
        xs[r][k] = X[(size_t)(row0 + r) * 128 + k];
    }
    __syncthreads();
    const int r  = threadIdx.x >> 3;
    const int c0 = (threadIdx.x & 7) * 5;
    float acc[5] = {0.f,0.f,0.f,0.f,0.f};
    for (int k = 0; k < 128; ++k) {
        float xv = xs[r][k];
        #pragma unroll
        for (int j = 0; j < 5; ++j)
            acc[j] = fmaf(xv, ws[k * NCLS + c0 + j], acc[j]);
    }
    #pragma unroll
    for (int j = 0; j < 5; ++j)
        Out[(size_t)(row0 + r) * NCLS + c0 + j] = acc[j] + bc[c0 + j];
}

extern "C" void kernel_launch(void* const* d_in, const int* in_sizes, int n_in,
                              void* d_out, int out_size, void* d_ws, size_t ws_size,
                              hipStream_t stream) {
    const float* x    = (const float*)d_in[0];
    const int*   ei   = (const int*)  d_in[1];
    // d_in[2] edge_weight: unused (matches reference)
    const float* W1   = (const float*)d_in[3];
    const float* al1  = (const float*)d_in[4];
    const float* ar1  = (const float*)d_in[5];
    const float* b1   = (const float*)d_in[6];
    const float* W2   = (const float*)d_in[7];
    const float* al2  = (const float*)d_in[8];
    const float* ar2  = (const float*)d_in[9];
    const float* b2   = (const float*)d_in[10];
    const float* Wc   = (const float*)d_in[11];
    const float* bc   = (const float*)d_in[12];
    float* out = (float*)d_out;

    const int* src = ei;
    const int* dst = ei + E_RAW;

    char* ws = (char*)d_ws;
    unsigned short* hb = (unsigned short*)(ws);        // 25.6 MB (bf16 h)
    unsigned short* whi1 = (unsigned short*)(ws + 25600000UL);   // 32 KB
    unsigned short* wlo1 = (unsigned short*)(ws + 25632768UL);
    unsigned short* whi2 = (unsigned short*)(ws + 25665536UL);
    unsigned short* wlo2 = (unsigned short*)(ws + 25698304UL);
    float* acc  = (float*)(ws + 51200000UL);           // 51.2 MB
    float* AL   = (float*)(ws + 102400000UL);          // 3.2 MB
    float* AR   = (float*)(ws + 105600000UL);          // 3.2 MB
    int*   csr  = (int*)  (ws + 108800000UL);          // 6.8 MB
    int*   cnt  = (int*)  (ws + 115600000UL);          // 0.4 MB
    int*   roff = (int*)  (ws + 116000000UL);          // 0.4 MB (+4)
    int*   rpos = (int*)  (ws + 116400004UL);          // 0.4 MB
    int*   part = (int*)  (ws + 116800004UL);          // 0.4 MB
    int*   bsum = (int*)  (ws + 117200004UL);          // 2 KB

    const int NB_N    = (NN + 255) / 256;              // 391
    const int gRaw    = (E_RAW + 255) / 256;           // 6250
    const int gTot    = (E_TOT + 255) / 256;           // 6641
    const int gRows32 = NN / 32;                       // 3125
    const int gGemm   = (NN + 63) / 64;                // 1563
    const int gGat    = NN / 4;                        // 25000

    // ---- weight prep (both layers) ----
    prep_w<<<128, 256, 0, stream>>>(W1, W2, whi1, wlo1, whi2, wlo2);

    // ---- CSR build (shared by both layers) ----
    csr_init_cnt<<<NB_N, 256, 0, stream>>>(cnt);
    csr_hist<<<gRaw, 256, 0, stream>>>(dst, cnt);
    scan_block<<<NB_N, 256, 0, stream>>>(cnt, part, bsum);
    scan_partials<<<1, 512, 0, stream>>>(bsum, NB_N);
    scan_add<<<NB_N, 256, 0, stream>>>(part, bsum, roff, rpos);
    csr_scatter<<<gTot, 256, 0, stream>>>(src, dst, rpos, csr);

    // ---- layer 1 ----
    gemm_mfma<<<gGemm, 256, 0, stream>>>(x, whi1, wlo1, al1, ar1, hb, AL, AR);
    gat_fused<<<gGat, 256, 0, stream>>>(roff, csr, AL, AR, hb, b1, acc);

    // ---- layer 2 ----
    gemm_mfma<<<gGemm, 256, 0, stream>>>(acc, whi2, wlo2, al2, ar2, hb, AL, AR);
    gat_fused<<<gGat, 256, 0, stream>>>(roff, csr, AL, AR, hb, b2, acc);

    // ---- classifier ----
    classifier<<<gRows32, 256, 0, stream>>>(acc, Wc, bc, out);
}

// Round 13
// 676.262 us; speedup vs baseline: 1.0929x; 1.0929x over previous
//
#include <hip/hip_runtime.h>
#include <hip/hip_bf16.h>
#include <math.h>

#define NN 100000
#define E_RAW 1600000
#define E_TOT 1700000
#define HEADS 8
#define CH 16
#define FDIM 128
#define NCLS 40
#define SLOPE 0.2f
#define NBKT 196          // ceil(100000 / 512) dst-buckets
#define BSH 9             // 512 nodes per bucket

typedef short bf16x8 __attribute__((ext_vector_type(8)));
typedef float f32x4  __attribute__((ext_vector_type(4)));

__device__ __forceinline__ float elu1(float v) { return v > 0.f ? v : expm1f(v); }

__device__ __forceinline__ unsigned short f2bf(float f) {   // RNE bf16
    unsigned int u = __float_as_uint(f);
    u += 0x7fffu + ((u >> 16) & 1u);
    return (unsigned short)(u >> 16);
}
__device__ __forceinline__ float bf2f(unsigned short h) {
    return __uint_as_float((unsigned int)h << 16);
}

// ===== prep_w: W [k][n] fp32 -> Wt hi/lo bf16 [n][k] (split-bf16) =====
__global__ __launch_bounds__(256) void prep_w(const float* __restrict__ W1,
                                              const float* __restrict__ W2,
                                              unsigned short* __restrict__ whi1,
                                              unsigned short* __restrict__ wlo1,
                                              unsigned short* __restrict__ whi2,
                                              unsigned short* __restrict__ wlo2) {
    int t = blockIdx.x * 256 + threadIdx.x;          // 0..32767
    const float* W = (t < 16384) ? W1 : W2;
    unsigned short* hi = (t < 16384) ? whi1 : whi2;
    unsigned short* lo = (t < 16384) ? wlo1 : wlo2;
    int e = t & 16383;
    int k = e & 127, n = e >> 7;
    float v = W[k * 128 + n];
    unsigned short h = f2bf(v);
    float r = v - bf2f(h);
    hi[e] = h; lo[e] = f2bf(r);
}

// ===== MFMA GEMM [NN,128]@[128,128] -> bf16 Hb + AL/AR epilogue =====
__global__ __launch_bounds__(256) void gemm_mfma(const float* __restrict__ X,
                                                 const unsigned short* __restrict__ Whi,
                                                 const unsigned short* __restrict__ Wlo,
                                                 const float* __restrict__ attl,
                                                 const float* __restrict__ attr,
                                                 unsigned short* __restrict__ Hb,
                                                 float* __restrict__ AL,
                                                 float* __restrict__ AR) {
    const int lane = threadIdx.x & 63;
    const int w    = threadIdx.x >> 6;       // wave 0..3
    const int m16  = lane & 15;              // A row / B col within frag
    const int koct = lane >> 4;              // k-octet 0..3
    const int rowA = blockIdx.x * 64 + w * 16 + m16;
    const int rowAc = rowA < NN ? rowA : NN - 1;

    f32x4 acc[8];
    #pragma unroll
    for (int c = 0; c < 8; ++c) acc[c] = (f32x4){0.f, 0.f, 0.f, 0.f};

    #pragma unroll
    for (int ks = 0; ks < 4; ++ks) {
        const int k0 = ks * 32;
        const float* xp = X + (size_t)rowAc * 128 + k0 + koct * 8;
        float xv[8];
        *(float4*)&xv[0] = *(const float4*)xp;
        *(float4*)&xv[4] = *(const float4*)(xp + 4);
        bf16x8 ahi, alo;
        #pragma unroll
        for (int j = 0; j < 8; ++j) {
            unsigned short h = f2bf(xv[j]);
            ahi[j] = (short)h;
            alo[j] = (short)f2bf(xv[j] - bf2f(h));
        }
        #pragma unroll
        for (int cf = 0; cf < 8; ++cf) {
            const size_t boff = (size_t)(cf * 16 + m16) * 128 + k0 + koct * 8;
            bf16x8 bhi = *(const bf16x8*)(Whi + boff);
            bf16x8 blo = *(const bf16x8*)(Wlo + boff);
            acc[cf] = __builtin_amdgcn_mfma_f32_16x16x32_bf16(ahi, bhi, acc[cf], 0, 0, 0);
            acc[cf] = __builtin_amdgcn_mfma_f32_16x16x32_bf16(alo, bhi, acc[cf], 0, 0, 0);
            acc[cf] = __builtin_amdgcn_mfma_f32_16x16x32_bf16(ahi, blo, acc[cf], 0, 0, 0);
        }
    }

    // epilogue: C/D layout col = lane&15, row = (lane>>4)*4 + reg  [m89]
    const int orow0 = blockIdx.x * 64 + w * 16 + koct * 4;
    #pragma unroll
    for (int cf = 0; cf < 8; ++cf) {
        const float lwv = attl[cf * 16 + m16];
        const float rwv = attr[cf * 16 + m16];
        #pragma unroll
        for (int r = 0; r < 4; ++r) {
            const int orow = orow0 + r;
            if (orow < NN)
                Hb[(size_t)orow * 128 + cf * 16 + m16] = f2bf(acc[cf][r]);
            float pl = acc[cf][r] * lwv;
            float pr = acc[cf][r] * rwv;
            #pragma unroll
            for (int off = 1; off < 16; off <<= 1) {
                pl += __shfl_xor(pl, off);
                pr += __shfl_xor(pr, off);
            }
            if (m16 == 0 && orow < NN) {
                AL[orow * 8 + cf] = pl;
                AR[orow * 8 + cf] = pr;
            }
        }
    }
}

// ================= CSR build =================
__global__ __launch_bounds__(256) void csr_init_cnt(int* __restrict__ cnt) {
    int i = blockIdx.x * 256 + threadIdx.x;
    if (i < NN) cnt[i] = 1;   // self-loop
}

__global__ __launch_bounds__(256) void csr_hist(const int* __restrict__ dst_a,
                                                int* __restrict__ cnt) {
    int e = blockIdx.x * 256 + threadIdx.x;
    if (e < E_RAW) atomicAdd(&cnt[dst_a[e]], 1);
}

__global__ __launch_bounds__(256) void scan_block(const int* __restrict__ cnt,
                                                  int* __restrict__ part,
                                                  int* __restrict__ bsum) {
    __shared__ int s[256];
    int i = blockIdx.x * 256 + threadIdx.x;
    int v = (i < NN) ? cnt[i] : 0;
    s[threadIdx.x] = v;
    __syncthreads();
    for (int off = 1; off < 256; off <<= 1) {
        int t = (threadIdx.x >= off) ? s[threadIdx.x - off] : 0;
        __syncthreads();
        s[threadIdx.x] += t;
        __syncthreads();
    }
    if (i < NN) part[i] = s[threadIdx.x] - v;
    if (threadIdx.x == 255) bsum[blockIdx.x] = s[255];
}

__global__ __launch_bounds__(512) void scan_partials(int* __restrict__ bsum, int nb) {
    __shared__ int s[512];
    int v = (threadIdx.x < nb) ? bsum[threadIdx.x] : 0;
    s[threadIdx.x] = v;
    __syncthreads();
    for (int off = 1; off < 512; off <<= 1) {
        int t = (threadIdx.x >= off) ? s[threadIdx.x - off] : 0;
        __syncthreads();
        s[threadIdx.x] += t;
        __syncthreads();
    }
    if (threadIdx.x < nb) bsum[threadIdx.x] = s[threadIdx.x] - v;
}

// roff = prefix; self-loop placed at roff[i]; rpos starts past it
__global__ __launch_bounds__(256) void scan_add(const int* __restrict__ part,
                                                const int* __restrict__ bsum,
                                                int* __restrict__ roff,
                                                int* __restrict__ rpos,
                                                int* __restrict__ csr) {
    int i = blockIdx.x * 256 + threadIdx.x;
    if (i < NN) {
        int v = part[i] + bsum[blockIdx.x];
        roff[i] = v;
        rpos[i] = v + 1;
        csr[v] = i;               // self-loop record, flag 0
    }
    if (i == NN) roff[NN] = E_TOT;
}

// bktCnt[b] = raw in-degree summed over the bucket's 512 nodes
__global__ __launch_bounds__(256) void bkt_cnt(const int* __restrict__ cnt,
                                               int* __restrict__ bktCnt) {
    __shared__ int red[8];
    const int b = blockIdx.x;
    const int base = b << BSH;
    int sum = 0;
    for (int i = threadIdx.x; i < (1 << BSH); i += 256) {
        int n = base + i;
        if (n < NN) sum += cnt[n] - 1;     // exclude self-loop
    }
    #pragma unroll
    for (int off = 1; off < 64; off <<= 1) sum += __shfl_xor(sum, off);
    if ((threadIdx.x & 63) == 0) red[threadIdx.x >> 6] = sum;
    __syncthreads();
    if (threadIdx.x == 0)
        bktCnt[b] = red[0] + red[1] + red[2] + red[3];
}

// exclusive scan of NBKT bucket counts; bpos = bktOff
__global__ __launch_bounds__(256) void bkt_scan(const int* __restrict__ bktCnt,
                                                int* __restrict__ bktOff,
                                                int* __restrict__ bpos) {
    __shared__ int s[256];
    int v = (threadIdx.x < NBKT) ? bktCnt[threadIdx.x] : 0;
    s[threadIdx.x] = v;
    __syncthreads();
    for (int off = 1; off < 256; off <<= 1) {
        int t = (threadIdx.x >= off) ? s[threadIdx.x - off] : 0;
        __syncthreads();
        s[threadIdx.x] += t;
        __syncthreads();
    }
    if (threadIdx.x < NBKT) {
        int e = s[threadIdx.x] - v;
        bktOff[threadIdx.x] = e;
        bpos[threadIdx.x]   = e;
    }
}

// pass 1: bin 4096 edges/block into dst-buckets, write 8B records in
// per-(block,bucket) contiguous runs (coalesced, ~1x line amplification)
__global__ __launch_bounds__(256) void bucket_stage(const int* __restrict__ src_a,
                                                    const int* __restrict__ dst_a,
                                                    int* __restrict__ bpos,
                                                    uint2* __restrict__ stage) {
    __shared__ int lcnt[NBKT];
    __shared__ int lbase[NBKT];
    for (int i = threadIdx.x; i < NBKT; i += 256) lcnt[i] = 0;
    __syncthreads();
    const int e0 = blockIdx.x * 4096 + threadIdx.x;
    int sv[16], dv[16], rk[16];
    #pragma unroll
    for (int it = 0; it < 16; ++it) {
        int e = e0 + it * 256;
        if (e < E_RAW) {
            sv[it] = src_a[e];
            dv[it] = dst_a[e];
            rk[it] = atomicAdd(&lcnt[dv[it] >> BSH], 1);
        } else dv[it] = -1;
    }
    __syncthreads();
    for (int i = threadIdx.x; i < NBKT; i += 256)
        lbase[i] = atomicAdd(&bpos[i], lcnt[i]);
    __syncthreads();
    #pragma unroll
    for (int it = 0; it < 16; ++it) {
        if (dv[it] >= 0) {
            int b = dv[it] >> BSH;
            unsigned int flag = (sv[it] == dv[it]) ? 0x80000000u : 0u;
            uint2 rec; rec.x = (unsigned int)sv[it] | flag; rec.y = (unsigned int)dv[it];
            stage[lbase[b] + rk[it]] = rec;
        }
    }
}

// pass 2: one block per bucket; scatter confined to its ~35KB CSR window
__global__ __launch_bounds__(256) void bucket_scatter(const int* __restrict__ bktOff,
                                                      const int* __restrict__ bpos,
                                                      const uint2* __restrict__ stage,
                                                      int* __restrict__ rpos,
                                                      int* __restrict__ csr) {
    const int b = blockIdx.x;
    const int lo = bktOff[b], hi = bpos[b];
    for (int i = lo + threadIdx.x; i < hi; i += 256) {
        uint2 rec = stage[i];
        int d = (int)rec.y;
        int p = atomicAdd(&rpos[d], 1);
        csr[p] = (int)rec.x;
    }
}

// ========== fused GAT layer: online softmax + bf16 gather + bias + ELU ==========
__global__ __launch_bounds__(256) void gat_fused(const int* __restrict__ roff,
                                                 const int* __restrict__ csr,
                                                 const float* __restrict__ AL,
                                                 const float* __restrict__ AR,
                                                 const unsigned short* __restrict__ Hb,
                                                 const float* __restrict__ bias,
                                                 float* __restrict__ Out) {
    const int lane = threadIdx.x & 63;
    const int n = blockIdx.x * 4 + (threadIdx.x >> 6);
    const int r0 = roff[n], r1 = roff[n + 1];

    // ---- pass A: online segment max + denom (8 lanes per head) ----
    const int hd = lane >> 3;
    const int t  = lane & 7;
    const float ard = AR[n * 8 + hd];
    float m = -3e38f, den = 0.f;
    for (int j = r0 + t; j < r1; j += 8) {
        int sw = csr[j];
        int s = sw & 0x7fffffff;
        float ev = AL[s * 8 + hd] + ard;
        ev = fmaxf(ev, SLOPE * ev);                       // LeakyReLU
        float mn = fmaxf(m, ev);
        float add = (sw >= 0) ? __expf(ev - mn) : 0.f;    // masked dups excluded
        den = fmaf(den, __expf(m - mn), add);
        m = mn;
    }
    #pragma unroll
    for (int off = 1; off < 8; off <<= 1) {
        float m2 = __shfl_xor(m, off), d2 = __shfl_xor(den, off);
        float mn = fmaxf(m, m2);
        den = den * __expf(m - mn) + d2 * __expf(m2 - mn);
        m = mn;
    }
    const float S = m + __logf(fmaxf(den, 1e-16f));

    // ---- pass B: 8 edges/iter, 8 lanes (one head's 16 feats) per edge ----
    const int ef = lane >> 3;
    const int fl = lane & 7;
    const float S_b  = __shfl(S,   fl * 8);
    const float ar_b = __shfl(ard, fl * 8);
    float4 a0 = make_float4(0.f,0.f,0.f,0.f), a1 = a0, a2 = a0, a3 = a0;
    for (int j = r0; j < r1; j += 8) {
        int jj = j + ef;
        if (jj < r1) {
            int sw = csr[jj];
            int s = sw & 0x7fffffff;
            float ev = AL[s * 8 + fl] + ar_b;
            ev = fmaxf(ev, SLOPE * ev);
            float alpha = (sw >= 0) ? __expf(ev - S_b) : 0.f;
            const unsigned short* hp = Hb + (size_t)s * 128 + fl * 16;
            const uint4 q0 = *(const uint4*)hp;
            const uint4 q1 = *(const uint4*)(hp + 8);
            a0.x = fmaf(__uint_as_float(q0.x << 16),          alpha, a0.x);
            a0.y = fmaf(__uint_as_float(q0.x & 0xffff0000u),  alpha, a0.y);
            a0.z = fmaf(__uint_as_float(q0.y << 16),          alpha, a0.z);
            a0.w = fmaf(__uint_as_float(q0.y & 0xffff0000u),  alpha, a0.w);
            a1.x = fmaf(__uint_as_float(q0.z << 16),          alpha, a1.x);
            a1.y = fmaf(__uint_as_float(q0.z & 0xffff0000u),  alpha, a1.y);
            a1.z = fmaf(__uint_as_float(q0.w << 16),          alpha, a1.z);
            a1.w = fmaf(__uint_as_float(q0.w & 0xffff0000u),  alpha, a1.w);
            a2.x = fmaf(__uint_as_float(q1.x << 16),          alpha, a2.x);
            a2.y = fmaf(__uint_as_float(q1.x & 0xffff0000u),  alpha, a2.y);
            a2.z = fmaf(__uint_as_float(q1.y << 16),          alpha, a2.z);
            a2.w = fmaf(__uint_as_float(q1.y & 0xffff0000u),  alpha, a2.w);
            a3.x = fmaf(__uint_as_float(q1.z << 16),          alpha, a3.x);
            a3.y = fmaf(__uint_as_float(q1.z & 0xffff0000u),  alpha, a3.y);
            a3.z = fmaf(__uint_as_float(q1.w << 16),          alpha, a3.z);
            a3.w = fmaf(__uint_as_float(q1.w & 0xffff0000u),  alpha, a3.w);
        }
    }
    #pragma unroll
    for (int off = 8; off < 64; off <<= 1) {
        a0.x += __shfl_xor(a0.x, off); a0.y += __shfl_xor(a0.y, off);
        a0.z += __shfl_xor(a0.z, off); a0.w += __shfl_xor(a0.w, off);
        a1.x += __shfl_xor(a1.x, off); a1.y += __shfl_xor(a1.y, off);
        a1.z += __shfl_xor(a1.z, off); a1.w += __shfl_xor(a1.w, off);
        a2.x += __shfl_xor(a2.x, off); a2.y += __shfl_xor(a2.y, off);
        a2.z += __shfl_xor(a2.z, off); a2.w += __shfl_xor(a2.w, off);
        a3.x += __shfl_xor(a3.x, off); a3.y += __shfl_xor(a3.y, off);
        a3.z += __shfl_xor(a3.z, off); a3.w += __shfl_xor(a3.w, off);
    }
    if (lane < 8) {
        const float4* bp = (const float4*)(bias + lane * 16);
        float4 b0 = bp[0], b1 = bp[1], b2 = bp[2], b3 = bp[3];
        a0.x = elu1(a0.x + b0.x); a0.y = elu1(a0.y + b0.y);
        a0.z = elu1(a0.z + b0.z); a0.w = elu1(a0.w + b0.w);
        a1.x = elu1(a1.x + b1.x); a1.y = elu1(a1.y + b1.y);
        a1.z = elu1(a1.z + b1.z); a1.w = elu1(a1.w + b1.w);
        a2.x = elu1(a2.x + b2.x); a2.y = elu1(a2.y + b2.y);
        a2.z = elu1(a2.z + b2.z); a2.w = elu1(a2.w + b2.w);
        a3.x = elu1(a3.x + b3.x); a3.y = elu1(a3.y + b3.y);
        a3.z = elu1(a3.z + b3.z); a3.w = elu1(a3.w + b3.w);
        float4* op = (float4*)(Out + (size_t)n * 128 + lane * 16);
        op[0] = a0; op[1] = a1; op[2] = a2; op[3] = a3;
    }
}

// ================= classifier: [NN,128] @ [128,40] + bc =================
__global__ __launch_bounds__(256) void classifier(const float* __restrict__ X,
                                                  const float* __restrict__ Wc,
                                                  const float* __restrict__ bc,
                                                  float* __restrict__ Out) {
    __shared__ float ws[128 * NCLS];
    __shared__ float xs[32][132];
    for (int i = threadIdx.x; i < 128 * NCLS; i += 256) ws[i] = Wc[i];
    const int row0 = blockIdx.x << 5;
    for (int i = threadIdx.x; i < 32 * 128; i += 256) {
        int r = i >> 7, k = i & 127;
        xs[r][k] = X[(size_t)(row0 + r) * 128 + k];
    }
    __syncthreads();
    const int r  = threadIdx.x >> 3;
    const int c0 = (threadIdx.x & 7) * 5;
    float acc[5] = {0.f,0.f,0.f,0.f,0.f};
    for (int k = 0; k < 128; ++k) {
        float xv = xs[r][k];
        #pragma unroll
        for (int j = 0; j < 5; ++j)
            acc[j] = fmaf(xv, ws[k * NCLS + c0 + j], acc[j]);
    }
    #pragma unroll
    for (int j = 0; j < 5; ++j)
        Out[(size_t)(row0 + r) * NCLS + c0 + j] = acc[j] + bc[c0 + j];
}

extern "C" void kernel_launch(void* const* d_in, const int* in_sizes, int n_in,
                              void* d_out, int out_size, void* d_ws, size_t ws_size,
                              hipStream_t stream) {
    const float* x    = (const float*)d_in[0];
    const int*   ei   = (const int*)  d_in[1];
    // d_in[2] edge_weight: unused (matches reference)
    const float* W1   = (const float*)d_in[3];
    const float* al1  = (const float*)d_in[4];
    const float* ar1  = (const float*)d_in[5];
    const float* b1   = (const float*)d_in[6];
    const float* W2   = (const float*)d_in[7];
    const float* al2  = (const float*)d_in[8];
    const float* ar2  = (const float*)d_in[9];
    const float* b2   = (const float*)d_in[10];
    const float* Wc   = (const float*)d_in[11];
    const float* bc   = (const float*)d_in[12];
    float* out = (float*)d_out;

    const int* src = ei;
    const int* dst = ei + E_RAW;

    char* ws = (char*)d_ws;
    unsigned short* hb = (unsigned short*)(ws);        // 25.6 MB (bf16 h)
    uint2* stage = (uint2*)(ws);                       // 12.8 MB, reused before hb is written
    unsigned short* whi1 = (unsigned short*)(ws + 25600000UL);   // 32 KB
    unsigned short* wlo1 = (unsigned short*)(ws + 25632768UL);
    unsigned short* whi2 = (unsigned short*)(ws + 25665536UL);
    unsigned short* wlo2 = (unsigned short*)(ws + 25698304UL);
    float* acc  = (float*)(ws + 51200000UL);           // 51.2 MB
    float* AL   = (float*)(ws + 102400000UL);          // 3.2 MB
    float* AR   = (float*)(ws + 105600000UL);          // 3.2 MB
    int*   csr  = (int*)  (ws + 108800000UL);          // 6.8 MB
    int*   cnt  = (int*)  (ws + 115600000UL);          // 0.4 MB
    int*   roff = (int*)  (ws + 116000000UL);          // 0.4 MB (+4)
    int*   rpos = (int*)  (ws + 116400004UL);          // 0.4 MB
    int*   part = (int*)  (ws + 116800004UL);          // 0.4 MB
    int*   bsum = (int*)  (ws + 117200004UL);          // 2 KB
    int*   bktCnt = (int*)(ws + 117300000UL);          // 784 B
    int*   bktOff = (int*)(ws + 117304000UL);
    int*   bpos   = (int*)(ws + 117308000UL);

    const int NB_N    = (NN + 255) / 256;              // 391
    const int gRaw    = (E_RAW + 255) / 256;           // 6250
    const int gStage  = (E_RAW + 4095) / 4096;         // 391
    const int gRows32 = NN / 32;                       // 3125
    const int gGemm   = (NN + 63) / 64;                // 1563
    const int gGat    = NN / 4;                        // 25000

    // ---- weight prep (both layers) ----
    prep_w<<<128, 256, 0, stream>>>(W1, W2, whi1, wlo1, whi2, wlo2);

    // ---- CSR build (shared by both layers) ----
    csr_init_cnt<<<NB_N, 256, 0, stream>>>(cnt);
    csr_hist<<<gRaw, 256, 0, stream>>>(dst, cnt);
    scan_block<<<NB_N, 256, 0, stream>>>(cnt, part, bsum);
    scan_partials<<<1, 512, 0, stream>>>(bsum, NB_N);
    scan_add<<<NB_N, 256, 0, stream>>>(part, bsum, roff, rpos, csr);
    bkt_cnt<<<NBKT, 256, 0, stream>>>(cnt, bktCnt);
    bkt_scan<<<1, 256, 0, stream>>>(bktCnt, bktOff, bpos);
    bucket_stage<<<gStage, 256, 0, stream>>>(src, dst, bpos, stage);
    bucket_scatter<<<NBKT, 256, 0, stream>>>(bktOff, bpos, stage, rpos, csr);

    // ---- layer 1 ----
    gemm_mfma<<<gGemm, 256, 0, stream>>>(x, whi1, wlo1, al1, ar1, hb, AL, AR);
    gat_fused<<<gGat, 256, 0, stream>>>(roff, csr, AL, AR, hb, b1, acc);

    // ---- layer 2 ----
    gemm_mfma<<<gGemm, 256, 0, stream>>>(acc, whi2, wlo2, al2, ar2, hb, AL, AR);
    gat_fused<<<gGat, 256, 0, stream>>>(roff, csr, AL, AR, hb, b2, acc);

    // ---- classifier ----
    classifier<<<gRows32, 256, 0, stream>>>(acc, Wc, bc, out);
}